// Round 1
// baseline (142.652 us; speedup 1.0000x reference)
//
#include <hip/hip_runtime.h>
#include <cstdint>

#define NN 100000
#define NE 1600000
#define HROW 288  // bytes per node in ws: 16 o-rows x (8 bf16 = 16B) + 16 bf16 bias

__device__ __forceinline__ unsigned short f2bf(float f) {
    unsigned int u = __float_as_uint(f);
    u += 0x7fffu + ((u >> 16) & 1u);   // round-to-nearest-even
    return (unsigned short)(u >> 16);
}
__device__ __forceinline__ float bf2f(unsigned int u) {
    return __uint_as_float(u << 16);
}

// Phase 1: per node n compute
//   out[n][o] = root_b[o] + sum_i x[n][i]*root_w[i][o]
//   h[n][o][d] = sum_i edge_w[d][o*16+i]*x[n][i]      (bf16, ws)
//   hbias[n][o] = sum_i edge_b[o*16+i]*x[n][i]        (bf16, ws)
__global__ __launch_bounds__(256) void node_pre_kernel(
    const float* __restrict__ x, const float* __restrict__ root_w,
    const float* __restrict__ root_b, const float* __restrict__ edge_w,
    const float* __restrict__ edge_b, float* __restrict__ out,
    unsigned char* __restrict__ hbuf)
{
    int n = blockIdx.x * 256 + threadIdx.x;
    if (n >= NN) return;
    const float4* xp = (const float4*)(x + (size_t)n * 16);
    float4 x0 = xp[0], x1 = xp[1], x2 = xp[2], x3 = xp[3];
    float xv[16] = {x0.x,x0.y,x0.z,x0.w, x1.x,x1.y,x1.z,x1.w,
                    x2.x,x2.y,x2.z,x2.w, x3.x,x3.y,x3.z,x3.w};

    // root transform (root_w/root_b reads are wave-uniform -> scalar loads)
    float r[16];
    #pragma unroll
    for (int o = 0; o < 16; ++o) {
        float s = root_b[o];
        #pragma unroll
        for (int i = 0; i < 16; ++i) s += xv[i] * root_w[i*16 + o];
        r[o] = s;
    }
    float4* op = (float4*)(out + (size_t)n * 16);
    op[0] = make_float4(r[0], r[1], r[2], r[3]);
    op[1] = make_float4(r[4], r[5], r[6], r[7]);
    op[2] = make_float4(r[8], r[9], r[10], r[11]);
    op[3] = make_float4(r[12], r[13], r[14], r[15]);

    unsigned char* hb = hbuf + (size_t)n * HROW;
    for (int o = 0; o < 16; ++o) {
        float z[8];
        #pragma unroll
        for (int d = 0; d < 8; ++d) {
            float s = 0.f;
            #pragma unroll
            for (int i = 0; i < 16; ++i) s += edge_w[d*256 + o*16 + i] * xv[i];
            z[d] = s;
        }
        uint4 pk;
        pk.x = (unsigned)f2bf(z[0]) | ((unsigned)f2bf(z[1]) << 16);
        pk.y = (unsigned)f2bf(z[2]) | ((unsigned)f2bf(z[3]) << 16);
        pk.z = (unsigned)f2bf(z[4]) | ((unsigned)f2bf(z[5]) << 16);
        pk.w = (unsigned)f2bf(z[6]) | ((unsigned)f2bf(z[7]) << 16);
        *(uint4*)(hb + o*16) = pk;
    }
    unsigned short ub[16];
    #pragma unroll
    for (int o = 0; o < 16; ++o) {
        float s = 0.f;
        #pragma unroll
        for (int i = 0; i < 16; ++i) s += edge_b[o*16 + i] * xv[i];
        ub[o] = f2bf(s);
    }
    uint4 pb0, pb1;
    pb0.x = (unsigned)ub[0]  | ((unsigned)ub[1]  << 16);
    pb0.y = (unsigned)ub[2]  | ((unsigned)ub[3]  << 16);
    pb0.z = (unsigned)ub[4]  | ((unsigned)ub[5]  << 16);
    pb0.w = (unsigned)ub[6]  | ((unsigned)ub[7]  << 16);
    pb1.x = (unsigned)ub[8]  | ((unsigned)ub[9]  << 16);
    pb1.y = (unsigned)ub[10] | ((unsigned)ub[11] << 16);
    pb1.z = (unsigned)ub[12] | ((unsigned)ub[13] << 16);
    pb1.w = (unsigned)ub[14] | ((unsigned)ub[15] << 16);
    *(uint4*)(hb + 256) = pb0;
    *(uint4*)(hb + 272) = pb1;
}

// Phase 2: one edge per 16-lane group; lane o computes msg[o] and atomically
// accumulates into out[dst][o].
__global__ __launch_bounds__(256) void edge_kernel(
    const float* __restrict__ edge_attr, const int* __restrict__ eidx,
    const unsigned char* __restrict__ hbuf, float* __restrict__ out)
{
    int g = threadIdx.x >> 4;
    int o = threadIdx.x & 15;
    int stride = gridDim.x * 16;
    for (int e = blockIdx.x * 16 + g; e < NE; e += stride) {
        int src = eidx[e];
        int dst = eidx[NE + e];
        const float4* ap = (const float4*)(edge_attr + (size_t)e * 8);
        float4 a0 = ap[0], a1 = ap[1];
        const unsigned char* hb = hbuf + (size_t)src * HROW;
        uint4 hv = *(const uint4*)(hb + o*16);
        unsigned short hbias = *(const unsigned short*)(hb + 256 + o*2);
        float m = bf2f(hbias);
        m += a0.x * bf2f(hv.x & 0xffffu);
        m += a0.y * bf2f(hv.x >> 16);
        m += a0.z * bf2f(hv.y & 0xffffu);
        m += a0.w * bf2f(hv.y >> 16);
        m += a1.x * bf2f(hv.z & 0xffffu);
        m += a1.y * bf2f(hv.z >> 16);
        m += a1.z * bf2f(hv.w & 0xffffu);
        m += a1.w * bf2f(hv.w >> 16);
        atomicAdd(out + (size_t)dst * 16 + o, m);
    }
}

// ---------- fallback path (ws too small): direct per-edge compute ----------
__global__ __launch_bounds__(256) void root_kernel(
    const float* __restrict__ x, const float* __restrict__ root_w,
    const float* __restrict__ root_b, float* __restrict__ out)
{
    int n = blockIdx.x * 256 + threadIdx.x;
    if (n >= NN) return;
    const float4* xp = (const float4*)(x + (size_t)n * 16);
    float4 x0 = xp[0], x1 = xp[1], x2 = xp[2], x3 = xp[3];
    float xv[16] = {x0.x,x0.y,x0.z,x0.w, x1.x,x1.y,x1.z,x1.w,
                    x2.x,x2.y,x2.z,x2.w, x3.x,x3.y,x3.z,x3.w};
    float r[16];
    #pragma unroll
    for (int o = 0; o < 16; ++o) {
        float s = root_b[o];
        #pragma unroll
        for (int i = 0; i < 16; ++i) s += xv[i] * root_w[i*16 + o];
        r[o] = s;
    }
    float4* op = (float4*)(out + (size_t)n * 16);
    op[0] = make_float4(r[0], r[1], r[2], r[3]);
    op[1] = make_float4(r[4], r[5], r[6], r[7]);
    op[2] = make_float4(r[8], r[9], r[10], r[11]);
    op[3] = make_float4(r[12], r[13], r[14], r[15]);
}

__global__ __launch_bounds__(256) void edge_direct_kernel(
    const float* __restrict__ x, const float* __restrict__ edge_attr,
    const float* __restrict__ edge_w, const float* __restrict__ edge_b,
    const int* __restrict__ eidx, float* __restrict__ out)
{
    int g = threadIdx.x >> 4;
    int o = threadIdx.x & 15;
    int stride = gridDim.x * 16;
    for (int e = blockIdx.x * 16 + g; e < NE; e += stride) {
        int src = eidx[e];
        int dst = eidx[NE + e];
        const float4* ap = (const float4*)(edge_attr + (size_t)e * 8);
        float4 a0 = ap[0], a1 = ap[1];
        float ea[8] = {a0.x,a0.y,a0.z,a0.w, a1.x,a1.y,a1.z,a1.w};
        const float4* xp = (const float4*)(x + (size_t)src * 16);
        float4 x0 = xp[0], x1 = xp[1], x2 = xp[2], x3 = xp[3];
        float xv[16] = {x0.x,x0.y,x0.z,x0.w, x1.x,x1.y,x1.z,x1.w,
                        x2.x,x2.y,x2.z,x2.w, x3.x,x3.y,x3.z,x3.w};
        float m = 0.f;
        #pragma unroll
        for (int i = 0; i < 16; ++i) {
            float w = edge_b[o*16 + i];
            #pragma unroll
            for (int d = 0; d < 8; ++d) w += ea[d] * edge_w[d*256 + o*16 + i];
            m += w * xv[i];
        }
        atomicAdd(out + (size_t)dst * 16 + o, m);
    }
}

extern "C" void kernel_launch(void* const* d_in, const int* in_sizes, int n_in,
                              void* d_out, int out_size, void* d_ws, size_t ws_size,
                              hipStream_t stream) {
    const float* x         = (const float*)d_in[0];
    const float* edge_attr = (const float*)d_in[1];
    const float* root_w    = (const float*)d_in[2];
    const float* root_b    = (const float*)d_in[3];
    const float* edge_w    = (const float*)d_in[4];
    const float* edge_b    = (const float*)d_in[5];
    const int*   eidx      = (const int*)d_in[6];
    float* out = (float*)d_out;

    if (ws_size >= (size_t)NN * HROW) {
        node_pre_kernel<<<(NN + 255) / 256, 256, 0, stream>>>(
            x, root_w, root_b, edge_w, edge_b, out, (unsigned char*)d_ws);
        edge_kernel<<<4096, 256, 0, stream>>>(
            edge_attr, eidx, (unsigned char*)d_ws, out);
    } else {
        root_kernel<<<(NN + 255) / 256, 256, 0, stream>>>(x, root_w, root_b, out);
        edge_direct_kernel<<<4096, 256, 0, stream>>>(
            x, edge_attr, edge_w, edge_b, eidx, out);
    }
}

// Round 2
// 99.429 us; speedup vs baseline: 1.4347x; 1.4347x over previous
//
#include <hip/hip_runtime.h>
#include <hip/hip_bf16.h>
#include <cstdint>

#define NN 100000
#define NE 1600000

using bf16x8 = __attribute__((ext_vector_type(8))) short;
using f32x4  = __attribute__((ext_vector_type(4))) float;

union BF8 { bf16x8 v; unsigned u[4]; };

__device__ __forceinline__ unsigned pk2(float lo, float hi) {
    union { __hip_bfloat162 b; unsigned u; } c;
    c.b = __float22bfloat162_rn(make_float2(lo, hi));
    return c.u;
}

// out[n][o] = root_b[o] + sum_i x[n][i]*root_w[i][o]
__global__ __launch_bounds__(256) void root_kernel(
    const float* __restrict__ x, const float* __restrict__ root_w,
    const float* __restrict__ root_b, float* __restrict__ out)
{
    int n = blockIdx.x * 256 + threadIdx.x;
    if (n >= NN) return;
    const float4* xp = (const float4*)(x + (size_t)n * 16);
    float4 x0 = xp[0], x1 = xp[1], x2 = xp[2], x3 = xp[3];
    float xv[16] = {x0.x,x0.y,x0.z,x0.w, x1.x,x1.y,x1.z,x1.w,
                    x2.x,x2.y,x2.z,x2.w, x3.x,x3.y,x3.z,x3.w};
    float r[16];
    #pragma unroll
    for (int o = 0; o < 16; ++o) {
        float s = root_b[o];
        #pragma unroll
        for (int i = 0; i < 16; ++i) s += xv[i] * root_w[i*16 + o];
        r[o] = s;
    }
    float4* op = (float4*)(out + (size_t)n * 16);
    op[0] = make_float4(r[0], r[1], r[2], r[3]);
    op[1] = make_float4(r[4], r[5], r[6], r[7]);
    op[2] = make_float4(r[8], r[9], r[10], r[11]);
    op[3] = make_float4(r[12], r[13], r[14], r[15]);
}

// One wave = 16 edges. msg_tile[16e x 16o] = Z[16e x 160k] @ W2[160k x 16o]
// Z[e, d*16+i]  = ea[e,d] * x[src[e], i]       (k = 0..127)
// Z[e, 128+i]   = x[src[e], i]                 (k = 128..143; 144..159 = 0)
// W2[d*16+i, o] = edge_w[d*256 + o*16 + i]
// W2[128+i, o]  = edge_b[o*16 + i]
// A-frag (16x32, lane l): row = l&15 (edge), k = ks*32 + (l>>4)*8 + j
//   -> d = ks*2 + (quad>>1), i = (quad&1)*8 + j  (quad = l>>4)
// B-frag (32x16, lane l): col = l&15 (o), same k rows.
// D (16x16, lane l): col = l&15 (o), row = quad*4 + r (edge).
__global__ __launch_bounds__(256) void edge_mfma_kernel(
    const float* __restrict__ edge_attr, const int* __restrict__ eidx,
    const float* __restrict__ x, const float* __restrict__ edge_w,
    const float* __restrict__ edge_b, float* __restrict__ out)
{
    const int lane = threadIdx.x & 63;
    const int row  = lane & 15;   // A-row (edge-in-tile) and B/D col (o)
    const int quad = lane >> 4;   // 0..3
    const int hi   = quad & 1;    // which 8-wide half of i
    const int q2   = quad >> 1;   // low/high d within the k=32 step

    // ---- constant B fragments (held in VGPRs for the whole kernel) ----
    BF8 bfrag[5];
    #pragma unroll
    for (int ks = 0; ks < 4; ++ks) {
        int d = ks * 2 + q2;
        const float4* p = (const float4*)(edge_w + d*256 + row*16 + hi*8);
        float4 w0 = p[0], w1 = p[1];
        bfrag[ks].u[0] = pk2(w0.x, w0.y);
        bfrag[ks].u[1] = pk2(w0.z, w0.w);
        bfrag[ks].u[2] = pk2(w1.x, w1.y);
        bfrag[ks].u[3] = pk2(w1.z, w1.w);
    }
    if (quad < 2) {
        const float4* p = (const float4*)(edge_b + row*16 + hi*8);
        float4 w0 = p[0], w1 = p[1];
        bfrag[4].u[0] = pk2(w0.x, w0.y);
        bfrag[4].u[1] = pk2(w0.z, w0.w);
        bfrag[4].u[2] = pk2(w1.x, w1.y);
        bfrag[4].u[3] = pk2(w1.z, w1.w);
    } else {
        bfrag[4].u[0] = bfrag[4].u[1] = bfrag[4].u[2] = bfrag[4].u[3] = 0;
    }

    const int ntiles = NE / 16;
    const int nw = gridDim.x * 4;
    int wid = blockIdx.x * 4 + (threadIdx.x >> 6);

    for (int t = wid; t < ntiles; t += nw) {
        const int e0 = t * 16;
        const int my_e = e0 + row;
        const int src = eidx[my_e];
        const float4* xp = (const float4*)(x + (size_t)src * 16 + hi * 8);
        float4 x0 = xp[0], x1 = xp[1];
        const float4* ap = (const float4*)(edge_attr + (size_t)my_e * 8);
        float4 a0 = ap[0], a1 = ap[1];
        // the 4 edge-attr scalars this lane needs (one per MFMA step)
        float ad0 = q2 ? a0.y : a0.x;
        float ad1 = q2 ? a0.w : a0.z;
        float ad2 = q2 ? a1.y : a1.x;
        float ad3 = q2 ? a1.w : a1.z;

        f32x4 acc = {0.f, 0.f, 0.f, 0.f};
        BF8 af;
        af.u[0] = pk2(ad0*x0.x, ad0*x0.y);
        af.u[1] = pk2(ad0*x0.z, ad0*x0.w);
        af.u[2] = pk2(ad0*x1.x, ad0*x1.y);
        af.u[3] = pk2(ad0*x1.z, ad0*x1.w);
        acc = __builtin_amdgcn_mfma_f32_16x16x32_bf16(af.v, bfrag[0].v, acc, 0, 0, 0);
        af.u[0] = pk2(ad1*x0.x, ad1*x0.y);
        af.u[1] = pk2(ad1*x0.z, ad1*x0.w);
        af.u[2] = pk2(ad1*x1.x, ad1*x1.y);
        af.u[3] = pk2(ad1*x1.z, ad1*x1.w);
        acc = __builtin_amdgcn_mfma_f32_16x16x32_bf16(af.v, bfrag[1].v, acc, 0, 0, 0);
        af.u[0] = pk2(ad2*x0.x, ad2*x0.y);
        af.u[1] = pk2(ad2*x0.z, ad2*x0.w);
        af.u[2] = pk2(ad2*x1.x, ad2*x1.y);
        af.u[3] = pk2(ad2*x1.z, ad2*x1.w);
        acc = __builtin_amdgcn_mfma_f32_16x16x32_bf16(af.v, bfrag[2].v, acc, 0, 0, 0);
        af.u[0] = pk2(ad3*x0.x, ad3*x0.y);
        af.u[1] = pk2(ad3*x0.z, ad3*x0.w);
        af.u[2] = pk2(ad3*x1.x, ad3*x1.y);
        af.u[3] = pk2(ad3*x1.z, ad3*x1.w);
        acc = __builtin_amdgcn_mfma_f32_16x16x32_bf16(af.v, bfrag[3].v, acc, 0, 0, 0);
        // step 4: A = xs (k=128..143), zero for quad>=2
        if (quad < 2) {
            af.u[0] = pk2(x0.x, x0.y);
            af.u[1] = pk2(x0.z, x0.w);
            af.u[2] = pk2(x1.x, x1.y);
            af.u[3] = pk2(x1.z, x1.w);
        } else {
            af.u[0] = af.u[1] = af.u[2] = af.u[3] = 0;
        }
        acc = __builtin_amdgcn_mfma_f32_16x16x32_bf16(af.v, bfrag[4].v, acc, 0, 0, 0);

        // scatter: lane covers edges e0 + quad*4 + r at column o=row
        #pragma unroll
        for (int r = 0; r < 4; ++r) {
            int ed = e0 + quad * 4 + r;
            int dst = eidx[NE + ed];
            atomicAdd(out + (size_t)dst * 16 + row, acc[r]);
        }
    }
}

extern "C" void kernel_launch(void* const* d_in, const int* in_sizes, int n_in,
                              void* d_out, int out_size, void* d_ws, size_t ws_size,
                              hipStream_t stream) {
    const float* x         = (const float*)d_in[0];
    const float* edge_attr = (const float*)d_in[1];
    const float* root_w    = (const float*)d_in[2];
    const float* root_b    = (const float*)d_in[3];
    const float* edge_w    = (const float*)d_in[4];
    const float* edge_b    = (const float*)d_in[5];
    const int*   eidx      = (const int*)d_in[6];
    float* out = (float*)d_out;

    root_kernel<<<(NN + 255) / 256, 256, 0, stream>>>(x, root_w, root_b, out);
    edge_mfma_kernel<<<2048, 256, 0, stream>>>(edge_attr, eidx, x, edge_w, edge_b, out);
}

// Round 3
// 94.472 us; speedup vs baseline: 1.5100x; 1.0525x over previous
//
#include <hip/hip_runtime.h>
#include <hip/hip_bf16.h>
#include <cstdint>

#define NN 100000
#define NE 1600000

using bf16x8 = __attribute__((ext_vector_type(8))) short;
using f32x4  = __attribute__((ext_vector_type(4))) float;

union BF8 { bf16x8 v; unsigned u[4]; };

__device__ __forceinline__ unsigned pk2(float lo, float hi) {
    union { __hip_bfloat162 b; unsigned u; } c;
    c.b = __float22bfloat162_rn(make_float2(lo, hi));
    return c.u;
}

// out[n][o] = root_b[o] + sum_i x[n][i]*root_w[i][o]
__global__ __launch_bounds__(256) void root_kernel(
    const float* __restrict__ x, const float* __restrict__ root_w,
    const float* __restrict__ root_b, float* __restrict__ out)
{
    int n = blockIdx.x * 256 + threadIdx.x;
    if (n >= NN) return;
    const float4* xp = (const float4*)(x + (size_t)n * 16);
    float4 x0 = xp[0], x1 = xp[1], x2 = xp[2], x3 = xp[3];
    float xv[16] = {x0.x,x0.y,x0.z,x0.w, x1.x,x1.y,x1.z,x1.w,
                    x2.x,x2.y,x2.z,x2.w, x3.x,x3.y,x3.z,x3.w};
    float r[16];
    #pragma unroll
    for (int o = 0; o < 16; ++o) {
        float s = root_b[o];
        #pragma unroll
        for (int i = 0; i < 16; ++i) s += xv[i] * root_w[i*16 + o];
        r[o] = s;
    }
    float4* op = (float4*)(out + (size_t)n * 16);
    op[0] = make_float4(r[0], r[1], r[2], r[3]);
    op[1] = make_float4(r[4], r[5], r[6], r[7]);
    op[2] = make_float4(r[8], r[9], r[10], r[11]);
    op[3] = make_float4(r[12], r[13], r[14], r[15]);
}

// One wave = one 16-edge tile per iteration, 2-deep software pipeline.
// msg_tile[16e x 16o] = Z[16e x 160k] @ W2[160k x 16o]  (see R2 notes)
// Pipeline ordering guarantees every awaited load was issued BEFORE the
// previous tile's atomics, so in-order vmcnt waits never include an
// outstanding atomic ack.
__global__ __launch_bounds__(256) void edge_mfma_kernel(
    const float* __restrict__ edge_attr, const int* __restrict__ eidx,
    const float* __restrict__ x, const float* __restrict__ edge_w,
    const float* __restrict__ edge_b, float* __restrict__ out)
{
    const int lane = threadIdx.x & 63;
    const int row  = lane & 15;   // A-row (edge-in-tile) and B/D col (o)
    const int quad = lane >> 4;   // 0..3
    const int hi   = quad & 1;    // which 8-wide half of i
    const int q2   = quad >> 1;   // low/high d within the k=32 step

    // ---- constant B fragments (VGPR-resident for whole kernel) ----
    BF8 bfrag[5];
    #pragma unroll
    for (int ks = 0; ks < 4; ++ks) {
        int d = ks * 2 + q2;
        const float4* p = (const float4*)(edge_w + d*256 + row*16 + hi*8);
        float4 w0 = p[0], w1 = p[1];
        bfrag[ks].u[0] = pk2(w0.x, w0.y);
        bfrag[ks].u[1] = pk2(w0.z, w0.w);
        bfrag[ks].u[2] = pk2(w1.x, w1.y);
        bfrag[ks].u[3] = pk2(w1.z, w1.w);
    }
    if (quad < 2) {
        const float4* p = (const float4*)(edge_b + row*16 + hi*8);
        float4 w0 = p[0], w1 = p[1];
        bfrag[4].u[0] = pk2(w0.x, w0.y);
        bfrag[4].u[1] = pk2(w0.z, w0.w);
        bfrag[4].u[2] = pk2(w1.x, w1.y);
        bfrag[4].u[3] = pk2(w1.z, w1.w);
    } else {
        bfrag[4].u[0] = bfrag[4].u[1] = bfrag[4].u[2] = bfrag[4].u[3] = 0;
    }

    const int ntiles = NE / 16;
    const int nw = gridDim.x * 4;
    int t = blockIdx.x * 4 + (threadIdx.x >> 6);
    if (t >= ntiles) return;

    // ---- prologue ----
    // idx stage 0 (tile t)
    int  src0 = eidx[t * 16 + row];
    int4 dst0 = *(const int4*)(eidx + NE + t * 16 + quad * 4);
    // idx stage 1 (tile t1, clamped)
    int t1  = t + nw;
    int tc1 = (t1 < ntiles) ? t1 : (ntiles - 1);
    int  src1 = eidx[tc1 * 16 + row];
    int4 dst1 = *(const int4*)(eidx + NE + tc1 * 16 + quad * 4);
    // payload stage 0 (x[src0], ea[t]) — waits only on idx t
    float4 xa0 = *(const float4*)(x + (size_t)src0 * 16 + hi * 8);
    float4 xb0 = *(const float4*)(x + (size_t)src0 * 16 + hi * 8 + 4);
    const float* ap0 = edge_attr + ((size_t)t * 16 + row) * 8;
    float4 ea00 = *(const float4*)(ap0);
    float4 ea10 = *(const float4*)(ap0 + 4);

    for (;;) {
        // (1) issue idx loads for t2
        int t2  = t1 + nw;
        int tc2 = (t2 < ntiles) ? t2 : (ntiles - 1);
        int  src2 = eidx[tc2 * 16 + row];
        int4 dst2 = *(const int4*)(eidx + NE + tc2 * 16 + quad * 4);
        // (2) issue payload loads for t1 (src1 loaded last iteration)
        float4 xa1 = *(const float4*)(x + (size_t)src1 * 16 + hi * 8);
        float4 xb1 = *(const float4*)(x + (size_t)src1 * 16 + hi * 8 + 4);
        const float* ap1 = edge_attr + ((size_t)tc1 * 16 + row) * 8;
        float4 ea01 = *(const float4*)(ap1);
        float4 ea11 = *(const float4*)(ap1 + 4);

        // (3) compute tile t from stage-0 payload
        float ad0 = q2 ? ea00.y : ea00.x;
        float ad1 = q2 ? ea00.w : ea00.z;
        float ad2 = q2 ? ea10.y : ea10.x;
        float ad3 = q2 ? ea10.w : ea10.z;

        f32x4 acc = {0.f, 0.f, 0.f, 0.f};
        BF8 af;
        af.u[0] = pk2(ad0*xa0.x, ad0*xa0.y);
        af.u[1] = pk2(ad0*xa0.z, ad0*xa0.w);
        af.u[2] = pk2(ad0*xb0.x, ad0*xb0.y);
        af.u[3] = pk2(ad0*xb0.z, ad0*xb0.w);
        acc = __builtin_amdgcn_mfma_f32_16x16x32_bf16(af.v, bfrag[0].v, acc, 0, 0, 0);
        af.u[0] = pk2(ad1*xa0.x, ad1*xa0.y);
        af.u[1] = pk2(ad1*xa0.z, ad1*xa0.w);
        af.u[2] = pk2(ad1*xb0.x, ad1*xb0.y);
        af.u[3] = pk2(ad1*xb0.z, ad1*xb0.w);
        acc = __builtin_amdgcn_mfma_f32_16x16x32_bf16(af.v, bfrag[1].v, acc, 0, 0, 0);
        af.u[0] = pk2(ad2*xa0.x, ad2*xa0.y);
        af.u[1] = pk2(ad2*xa0.z, ad2*xa0.w);
        af.u[2] = pk2(ad2*xb0.x, ad2*xb0.y);
        af.u[3] = pk2(ad2*xb0.z, ad2*xb0.w);
        acc = __builtin_amdgcn_mfma_f32_16x16x32_bf16(af.v, bfrag[2].v, acc, 0, 0, 0);
        af.u[0] = pk2(ad3*xa0.x, ad3*xa0.y);
        af.u[1] = pk2(ad3*xa0.z, ad3*xa0.w);
        af.u[2] = pk2(ad3*xb0.x, ad3*xb0.y);
        af.u[3] = pk2(ad3*xb0.z, ad3*xb0.w);
        acc = __builtin_amdgcn_mfma_f32_16x16x32_bf16(af.v, bfrag[3].v, acc, 0, 0, 0);
        if (quad < 2) {
            af.u[0] = pk2(xa0.x, xa0.y);
            af.u[1] = pk2(xa0.z, xa0.w);
            af.u[2] = pk2(xb0.x, xb0.y);
            af.u[3] = pk2(xb0.z, xb0.w);
        } else {
            af.u[0] = af.u[1] = af.u[2] = af.u[3] = 0;
        }
        acc = __builtin_amdgcn_mfma_f32_16x16x32_bf16(af.v, bfrag[4].v, acc, 0, 0, 0);

        // (4) atomics for tile t (issued AFTER next tiles' loads)
        atomicAdd(out + (size_t)dst0.x * 16 + row, acc[0]);
        atomicAdd(out + (size_t)dst0.y * 16 + row, acc[1]);
        atomicAdd(out + (size_t)dst0.z * 16 + row, acc[2]);
        atomicAdd(out + (size_t)dst0.w * 16 + row, acc[3]);

        // (5) rotate / advance
        if (t1 >= ntiles) break;
        t = t1; t1 = t2; tc1 = tc2;
        src0 = src1; dst0 = dst1;
        src1 = src2; dst1 = dst2;
        xa0 = xa1; xb0 = xb1; ea00 = ea01; ea10 = ea11;
    }
}

extern "C" void kernel_launch(void* const* d_in, const int* in_sizes, int n_in,
                              void* d_out, int out_size, void* d_ws, size_t ws_size,
                              hipStream_t stream) {
    const float* x         = (const float*)d_in[0];
    const float* edge_attr = (const float*)d_in[1];
    const float* root_w    = (const float*)d_in[2];
    const float* root_b    = (const float*)d_in[3];
    const float* edge_w    = (const float*)d_in[4];
    const float* edge_b    = (const float*)d_in[5];
    const int*   eidx      = (const int*)d_in[6];
    float* out = (float*)d_out;

    root_kernel<<<(NN + 255) / 256, 256, 0, stream>>>(x, root_w, root_b, out);
    edge_mfma_kernel<<<4096, 256, 0, stream>>>(edge_attr, eidx, x, edge_w, edge_b, out);
}